// Round 16
// baseline (233.394 us; speedup 1.0000x reference)
//
#include <hip/hip_runtime.h>
#include <math.h>

#define B_  256
#define IU  8
#define IC  1152
#define NU  10
#define US  16
#define CCH 9
#define NCH 128
#define BT  64
#define NBLK 512
#define XSP 516   // xs plane stride: 516 mod 32 = 4 -> staging writes spread banks
#define SBSTRIDE ((size_t)B_ * NU * US)   // floats per summed-s buffer (40,960)

// cache-bypassing accessors (coherence point = L3)
__device__ __forceinline__ float gld(const float* p) {
    return __hip_atomic_load(p, __ATOMIC_RELAXED, __HIP_MEMORY_SCOPE_AGENT);
}
__device__ __forceinline__ unsigned uld(const unsigned* p) {
    return __hip_atomic_load(p, __ATOMIC_RELAXED, __HIP_MEMORY_SCOPE_AGENT);
}
__device__ __forceinline__ void ust(unsigned* p, unsigned v) {
    __hip_atomic_store(p, v, __ATOMIC_RELAXED, __HIP_MEMORY_SCOPE_AGENT);
}

// ---------------- fence-free grid barrier, hierarchical release (R8/R9 proven) --
__device__ __forceinline__ void gridbar(unsigned* bar) {
    __syncthreads();
    if (threadIdx.x == 0) {
        const int bid = blockIdx.x;
        const int leaf = bid >> 3;        // 0..63
        const int mid  = bid >> 6;        // 0..7
        unsigned* myR1 = bar + (96 + leaf) * 32;
        unsigned g = uld(myR1);
        unsigned a = __hip_atomic_fetch_add(bar + leaf * 32, 1u,
                                            __ATOMIC_RELAXED, __HIP_MEMORY_SCOPE_AGENT);
        if (a == 7u) {
            ust(bar + leaf * 32, 0u);
            unsigned b2 = __hip_atomic_fetch_add(bar + (64 + mid) * 32, 1u,
                                                 __ATOMIC_RELAXED, __HIP_MEMORY_SCOPE_AGENT);
            if (b2 == 7u) {
                ust(bar + (64 + mid) * 32, 0u);
                unsigned c2 = __hip_atomic_fetch_add(bar + 72 * 32, 1u,
                                                     __ATOMIC_RELAXED, __HIP_MEMORY_SCOPE_AGENT);
                if (c2 == 7u) {
                    ust(bar + 72 * 32, 0u);
#pragma unroll
                    for (int k = 0; k < 8; k++)
                        ust(bar + (80 + k) * 32, g + 1u);
                }
                while (uld(bar + (80 + mid) * 32) == g)
                    __builtin_amdgcn_s_sleep(8);
#pragma unroll
                for (int j = 0; j < 8; j++)
                    ust(bar + (96 + mid * 8 + j) * 32, g + 1u);
            }
        }
        while (uld(myR1) == g)
            __builtin_amdgcn_s_sleep(16);
    }
    __syncthreads();
}

// ---------------- persistent routing kernel v14 -------------------------------
// = R15 base, with the chunk-partial reduction moved into the memory system:
// s-phase atomicAdds into sb[iter][b][160] (final sums at L3 after the barrier);
// agree computes v INLINE from sb (same load count as reading vb before, plus
// ~20 VALU/bl for msq+f). Squash phases and their barrier are gone (5 barriers).
__global__ __launch_bounds__(256, 2) void mega(const float* __restrict__ x,
                                               const float* __restrict__ W,
                                               float* __restrict__ sb,     // 3 buffers
                                               float* __restrict__ bij,
                                               float* __restrict__ esum,   // [2][16]
                                               unsigned* __restrict__ ticket, // [2][128]
                                               float* __restrict__ out,
                                               unsigned* __restrict__ bar) {
    __shared__ float4 ws[CCH * NU * 2 * 16];            // 46080 B raw W [cc][d][h][uq]
    __shared__ __align__(16) float xs[CCH * XSP];       // 18576 B  [cc][bl*8+i] padded
    __shared__ float aux[NU * US];                      // 640 B (final squash)
    __shared__ float cs[NU * CCH];                      // 360 B (c_ij slice)
    __shared__ int lastflag;

    const int tid = threadIdx.x;
    const int bid = blockIdx.x;
    const int grp = bid & 7;
    const int slot_ = bid >> 3;
    const int ch = ((slot_ >> 2) << 3) | grp;   // chunk pinned to one XCD (perf-only)
    const int bt = slot_ & 3;
    const int b0 = bt * BT, c0 = ch * CCH;

    // ---- one-time staging (plain cached loads: read-only inputs) ----
    const float4* wg = (const float4*)W + (size_t)c0 * 320;
    for (int q = tid; q < CCH * NU * 32; q += 256) {
        int h = q & 1, u = (q >> 1) & 15, cd = q >> 5;
        ws[(cd * 2 + h) * 16 + u] = wg[q];
    }
    for (int idx = tid; idx < CCH * BT * IU; idx += 256) {
        int cc = idx % CCH;
        int r = idx / CCH;                       // r = bl*8 + i
        xs[cc * XSP + r] = x[((size_t)(b0 + (r >> 3)) * IU + (r & 7)) * IC + c0 + cc];
    }

    const int uq = tid & 15;
    const int bs = tid >> 4;

    for (int iter = 0; iter < 3; ++iter) {
        float* sbb = sb + (size_t)iter * SBSTRIDE;   // this iteration's summed-s

        // ---- c_ij slice: uniform (iter 0) or exp(bij)/esum ----
        __syncthreads();
        if (iter == 0) {
            for (int q = tid; q < NU * CCH; q += 256) cs[q] = 1.0f;
        } else {
            for (int q = tid; q < NU * CCH; q += 256) {
                int d = q / CCH, cc = q - d * CCH;
                float es = gld(esum + (iter - 1) * 16 + d);
                cs[q] = expf(gld(bij + (size_t)d * IC + c0 + cc)) / es;
            }
        }
        __syncthreads();
        const float scale = iter ? 1.0f : (1.0f / (float)IC);   // softmax(0) uniform

        // ---- s phase: accumulate straight into sb via device atomics ----
        {
            float acc[4][NU];
#pragma unroll
            for (int bb = 0; bb < 4; bb++)
#pragma unroll
                for (int d = 0; d < NU; d++) acc[bb][d] = 0.0f;

#pragma unroll 3
            for (int cc = 0; cc < CCH; cc++) {
                float4 xv0[4], xv1[4];
#pragma unroll
                for (int bb = 0; bb < 4; bb++) {
                    const float4* xp = (const float4*)(xs + cc * XSP + (bs + 16 * bb) * IU);
                    xv0[bb] = xp[0]; xv1[bb] = xp[1];
                }
#pragma unroll
                for (int d = 0; d < NU; d++) {
                    float4 w0 = ws[((cc * NU + d) * 2 + 0) * 16 + uq];
                    float4 w1 = ws[((cc * NU + d) * 2 + 1) * 16 + uq];
                    const float cw = cs[d * CCH + cc];
#pragma unroll
                    for (int bb = 0; bb < 4; bb++) {
                        float uh = w0.x * xv0[bb].x + w0.y * xv0[bb].y + w0.z * xv0[bb].z + w0.w * xv0[bb].w
                                 + w1.x * xv1[bb].x + w1.y * xv1[bb].y + w1.z * xv1[bb].z + w1.w * xv1[bb].w;
                        acc[bb][d] = fmaf(cw, uh, acc[bb][d]);
                    }
                }
            }
#pragma unroll
            for (int bb = 0; bb < 4; bb++) {
                const int b = b0 + bs + 16 * bb;
                float* rowp = sbb + (size_t)b * (NU * US) + uq;
#pragma unroll
                for (int d = 0; d < NU; d++)
                    atomicAdd(rowp + d * US, acc[bb][d] * scale);
            }
        }
        gridbar(bar);   // all atomics at L3 -> sb final; bij/esum published later

        if (iter == 2) {
            // ---- final output: blocks 0..255 read their 160 summed values ----
            if (bid < B_) {
                if (tid < NU * US) aux[tid] = sbb[(size_t)bid * (NU * US) + tid];
                __syncthreads();
                if (tid < NU * US) {
                    float s = aux[tid];
                    float msq = 0.0f;
#pragma unroll
                    for (int dd = 0; dd < NU; dd++) {
                        float t = aux[dd * US + uq];
                        msq = fmaf(t, t, msq);
                    }
                    float f = msq / ((1.0f + msq) * sqrtf(msq));
                    out[(size_t)bid * (NU * US) + tid] = s * f;   // kernel-end flush
                }
            }
            return;
        }

        // ---- agree phase with INLINE squash: thread (uq, cl<9) reads summed s,
        //      computes v on the fly; bij atomics + esum ticket epilogue ----
        {
            const int cl = tid >> 4;
            if (cl < CCH) {
                float4 wA[NU], wB[NU];
#pragma unroll
                for (int d = 0; d < NU; d++) {
                    wA[d] = ws[((cl * NU + d) * 2 + 0) * 16 + uq];
                    wB[d] = ws[((cl * NU + d) * 2 + 1) * 16 + uq];
                }
                float accd[NU];
#pragma unroll
                for (int d = 0; d < NU; d++) accd[d] = 0.0f;
                const int bstag = (cl & 3) * 7;
#pragma unroll 4
                for (int blx = 0; blx < BT; blx++) {
                    const int bl = (blx + bstag) & 63;
                    // summed s for this (batch, uq): 10 cached scalar loads
                    const float* sp_ = sbb + (size_t)(b0 + bl) * (NU * US) + uq;
                    float sv[NU];
#pragma unroll
                    for (int d = 0; d < NU; d++) sv[d] = sp_[d * US];
                    float msq = 0.0f;
#pragma unroll
                    for (int d = 0; d < NU; d++) msq = fmaf(sv[d], sv[d], msq);
                    const float f = msq / ((1.0f + msq) * sqrtf(msq));

                    const float* xp = xs + cl * XSP + bl * IU;
                    float4 x0 = *(const float4*)xp;
                    float4 x1 = *(const float4*)(xp + 4);
#pragma unroll
                    for (int d = 0; d < NU; d++) {
                        float uh = wA[d].x * x0.x + wA[d].y * x0.y + wA[d].z * x0.z + wA[d].w * x0.w
                                 + wB[d].x * x1.x + wB[d].y * x1.y + wB[d].z * x1.z + wB[d].w * x1.w;
                        accd[d] = fmaf(uh, sv[d] * f, accd[d]);
                    }
                }
#pragma unroll
                for (int d = 0; d < NU; d++) {
                    float a = accd[d];
                    a += __shfl_xor(a, 1, 64);
                    a += __shfl_xor(a, 2, 64);
                    a += __shfl_xor(a, 4, 64);
                    a += __shfl_xor(a, 8, 64);
                    if (uq == 0)
                        atomicAdd(bij + (size_t)d * IC + c0 + cl, a * (1.0f / (float)B_));
                }
            }
            // drain this block's atomics (vmcnt 0) before taking the ticket
            __syncthreads();
            if (tid == 0) {
                unsigned old = __hip_atomic_fetch_add(ticket + iter * 128 + ch, 1u,
                                                      __ATOMIC_RELAXED,
                                                      __HIP_MEMORY_SCOPE_AGENT);
                lastflag = (old == 3u);
            }
            __syncthreads();
            if (lastflag && tid < NU) {   // bij for this chunk is final
                float es = 0.0f;
#pragma unroll
                for (int cc = 0; cc < CCH; cc++)
                    es += expf(gld(bij + (size_t)tid * IC + c0 + cc));
                atomicAdd(esum + iter * 16 + tid, es);
            }
        }
        gridbar(bar);   // publishes esum + bij for next iteration's cs prologue
    }
}

extern "C" void kernel_launch(void* const* d_in, const int* in_sizes, int n_in,
                              void* d_out, int out_size, void* d_ws, size_t ws_size,
                              hipStream_t stream) {
    (void)in_sizes; (void)n_in; (void)out_size; (void)ws_size;
    const float* x = (const float*)d_in[0];   // [256, 8, 1152]
    const float* W = (const float*)d_in[1];   // [1, 1152, 10, 16, 8]
    float* out = (float*)d_out;               // [256, 10, 16] fp32

    // workspace: bar(5120 u32) | ticket(256 u32) | esum(32 f) | bij | sb x3
    unsigned* bar = (unsigned*)d_ws;
    unsigned* ticket = bar + 5120;
    float* esum = (float*)(ticket + 256);
    float* bij = esum + 32;
    float* sb  = bij + (size_t)NU * IC;

    // zero bar + ticket + esum + bij + sb (atomic accumulators) — replayed per graph
    size_t zbytes = (5120 + 256) * 4 + 32 * 4 + (size_t)NU * IC * 4
                  + 3 * SBSTRIDE * 4;
    hipMemsetAsync(d_ws, 0, zbytes, stream);
    mega<<<NBLK, 256, 0, stream>>>(x, W, sb, bij, esum, ticket, out, bar);
}

// Round 17
// 187.528 us; speedup vs baseline: 1.2446x; 1.2446x over previous
//
#include <hip/hip_runtime.h>
#include <math.h>

#define B_  256
#define IU  8
#define IC  1152
#define NU  10
#define US  16
#define CCH 9
#define NCH 128
#define BT  64
#define NBLK 512
#define XSP 516   // xs plane stride: 516 mod 32 = 4 -> staging writes spread banks
#define SPSTRIDE ((size_t)NCH * B_ * NU * US)   // floats per sp buffer (R12 layout)

// cache-bypassing accessors (coherence point = L3)
__device__ __forceinline__ float gld(const float* p) {
    return __hip_atomic_load(p, __ATOMIC_RELAXED, __HIP_MEMORY_SCOPE_AGENT);
}
__device__ __forceinline__ void gst(float* p, float v) {
    __hip_atomic_store(p, v, __ATOMIC_RELAXED, __HIP_MEMORY_SCOPE_AGENT);
}
__device__ __forceinline__ unsigned uld(const unsigned* p) {
    return __hip_atomic_load(p, __ATOMIC_RELAXED, __HIP_MEMORY_SCOPE_AGENT);
}
__device__ __forceinline__ void ust(unsigned* p, unsigned v) {
    __hip_atomic_store(p, v, __ATOMIC_RELAXED, __HIP_MEMORY_SCOPE_AGENT);
}

// ---------------- fence-free grid barrier, hierarchical release ----------------
// (R8/R9-proven protocol; R17: wake quanta halved — leaf 16->8, mid 8->4.
//  <=8 pollers/line so poll traffic stays trivial.)
__device__ __forceinline__ void gridbar(unsigned* bar) {
    __syncthreads();
    if (threadIdx.x == 0) {
        const int bid = blockIdx.x;
        const int leaf = bid >> 3;        // 0..63
        const int mid  = bid >> 6;        // 0..7
        unsigned* myR1 = bar + (96 + leaf) * 32;
        unsigned g = uld(myR1);
        unsigned a = __hip_atomic_fetch_add(bar + leaf * 32, 1u,
                                            __ATOMIC_RELAXED, __HIP_MEMORY_SCOPE_AGENT);
        if (a == 7u) {
            ust(bar + leaf * 32, 0u);
            unsigned b2 = __hip_atomic_fetch_add(bar + (64 + mid) * 32, 1u,
                                                 __ATOMIC_RELAXED, __HIP_MEMORY_SCOPE_AGENT);
            if (b2 == 7u) {
                ust(bar + (64 + mid) * 32, 0u);
                unsigned c2 = __hip_atomic_fetch_add(bar + 72 * 32, 1u,
                                                     __ATOMIC_RELAXED, __HIP_MEMORY_SCOPE_AGENT);
                if (c2 == 7u) {
                    ust(bar + 72 * 32, 0u);
#pragma unroll
                    for (int k = 0; k < 8; k++)
                        ust(bar + (80 + k) * 32, g + 1u);
                }
                while (uld(bar + (80 + mid) * 32) == g)
                    __builtin_amdgcn_s_sleep(4);
#pragma unroll
                for (int j = 0; j < 8; j++)
                    ust(bar + (96 + mid * 8 + j) * 32, g + 1u);
            }
        }
        while (uld(myR1) == g)
            __builtin_amdgcn_s_sleep(8);
    }
    __syncthreads();
}

// ---------------- persistent routing kernel v13 (R15, converged structure) -----
// R12 base + XSP staging pad + esum incremental softmax denominator.
__global__ __launch_bounds__(256, 2) void mega(const float* __restrict__ x,
                                               const float* __restrict__ W,
                                               float* __restrict__ sp,     // 3 buffers
                                               float* __restrict__ vb0,
                                               float* __restrict__ vb1,
                                               float* __restrict__ bij,
                                               float* __restrict__ esum,   // [2][16]
                                               unsigned* __restrict__ ticket, // [2][128]
                                               float* __restrict__ out,
                                               unsigned* __restrict__ bar) {
    __shared__ float4 ws[CCH * NU * 2 * 16];            // 46080 B raw W [cc][d][h][uq]
    __shared__ __align__(16) float xs[CCH * XSP];       // 18576 B  [cc][bl*8+i] padded
    __shared__ float aux[NU * US];                      // 640 B (squash s-vector)
    __shared__ float cs[NU * CCH];                      // 360 B (c_ij slice)
    __shared__ int lastflag;

    const int tid = threadIdx.x;
    const int bid = blockIdx.x;
    const int grp = bid & 7;
    const int slot_ = bid >> 3;
    const int ch = ((slot_ >> 2) << 3) | grp;   // chunk pinned to one XCD (perf-only)
    const int bt = slot_ & 3;
    const int b0 = bt * BT, c0 = ch * CCH;

    // ---- one-time staging (plain cached loads: read-only inputs) ----
    const float4* wg = (const float4*)W + (size_t)c0 * 320;
    for (int q = tid; q < CCH * NU * 32; q += 256) {
        int h = q & 1, u = (q >> 1) & 15, cd = q >> 5;
        ws[(cd * 2 + h) * 16 + u] = wg[q];
    }
    for (int idx = tid; idx < CCH * BT * IU; idx += 256) {
        int cc = idx % CCH;
        int r = idx / CCH;                       // r = bl*8 + i
        xs[cc * XSP + r] = x[((size_t)(b0 + (r >> 3)) * IU + (r & 7)) * IC + c0 + cc];
    }

    const int uq = tid & 15;
    const int bs = tid >> 4;

    for (int iter = 0; iter < 3; ++iter) {
        float* spb = sp + (size_t)iter * SPSTRIDE;   // this iteration's buffer

        // ---- c_ij slice: uniform (iter 0) or exp(bij)/esum; denominator was
        //      accumulated incrementally during the previous agree phase ----
        __syncthreads();
        if (iter == 0) {
            for (int q = tid; q < NU * CCH; q += 256) cs[q] = 1.0f;
        } else {
            for (int q = tid; q < NU * CCH; q += 256) {
                int d = q / CCH, cc = q - d * CCH;
                float es = gld(esum + (iter - 1) * 16 + d);
                cs[q] = expf(gld(bij + (size_t)d * IC + c0 + cc)) / es;
            }
        }
        __syncthreads();
        const float scale = iter ? 1.0f : (1.0f / (float)IC);   // softmax(0) uniform

        // ---- s phase ----
        {
            float acc[4][NU];
#pragma unroll
            for (int bb = 0; bb < 4; bb++)
#pragma unroll
                for (int d = 0; d < NU; d++) acc[bb][d] = 0.0f;

#pragma unroll 3
            for (int cc = 0; cc < CCH; cc++) {
                float4 xv0[4], xv1[4];
#pragma unroll
                for (int bb = 0; bb < 4; bb++) {
                    const float4* xp = (const float4*)(xs + cc * XSP + (bs + 16 * bb) * IU);
                    xv0[bb] = xp[0]; xv1[bb] = xp[1];
                }
#pragma unroll
                for (int d = 0; d < NU; d++) {
                    float4 w0 = ws[((cc * NU + d) * 2 + 0) * 16 + uq];
                    float4 w1 = ws[((cc * NU + d) * 2 + 1) * 16 + uq];
                    const float cw = cs[d * CCH + cc];
#pragma unroll
                    for (int bb = 0; bb < 4; bb++) {
                        float uh = w0.x * xv0[bb].x + w0.y * xv0[bb].y + w0.z * xv0[bb].z + w0.w * xv0[bb].w
                                 + w1.x * xv1[bb].x + w1.y * xv1[bb].y + w1.z * xv1[bb].z + w1.w * xv1[bb].w;
                        acc[bb][d] = fmaf(cw, uh, acc[bb][d]);
                    }
                }
            }
#pragma unroll
            for (int bb = 0; bb < 4; bb++) {
                const int b = b0 + bs + 16 * bb;
#pragma unroll
                for (int d = 0; d < NU; d++)
                    gst(spb + (((size_t)ch * B_ + b) * NU + d) * US + uq, acc[bb][d] * scale);
            }
        }
        gridbar(bar);

        // ---- squash: blocks 0..255, one batch each; cached float4 loads;
        //      part-combine via shfl ----
        if (bid < B_) {
            if (tid < 160) {
                const int part = tid & 3;     // 4 chunk-quarters in adjacent lanes
                const int sl = tid >> 2;      // float4 slot 0..39 of the 160-vec
                const float4* s4p = (const float4*)spb;
                float4 a = make_float4(0.f, 0.f, 0.f, 0.f);
#pragma unroll 8
                for (int k = 0; k < 32; ++k) {
                    float4 t = s4p[((size_t)(part * 32 + k) * B_ + bid) * 40 + sl];
                    a.x += t.x; a.y += t.y; a.z += t.z; a.w += t.w;
                }
                a.x += __shfl_xor(a.x, 1, 64); a.y += __shfl_xor(a.y, 1, 64);
                a.z += __shfl_xor(a.z, 1, 64); a.w += __shfl_xor(a.w, 1, 64);
                a.x += __shfl_xor(a.x, 2, 64); a.y += __shfl_xor(a.y, 2, 64);
                a.z += __shfl_xor(a.z, 2, 64); a.w += __shfl_xor(a.w, 2, 64);
                if (part == 0) {
                    aux[sl * 4 + 0] = a.x; aux[sl * 4 + 1] = a.y;
                    aux[sl * 4 + 2] = a.z; aux[sl * 4 + 3] = a.w;
                }
            }
            __syncthreads();
            if (tid < NU * US) {
                float s = aux[tid];
                float msq = 0.0f;
#pragma unroll
                for (int dd = 0; dd < NU; dd++) {
                    float t = aux[dd * US + uq];
                    msq = fmaf(t, t, msq);
                }
                float f = msq / ((1.0f + msq) * sqrtf(msq));
                if (iter == 2)
                    out[(size_t)bid * (NU * US) + tid] = s * f;   // kernel-end flush
                else {
                    float* vdst = (iter == 0) ? vb0 : vb1;
                    gst(vdst + (size_t)bid * (NU * US) + tid, s * f);
                }
            }
        }
        if (iter == 2) return;
        gridbar(bar);

        // ---- agree phase + esum ticket epilogue ----
        {
            const int cl = tid >> 4;
            const float* vb = (iter == 0) ? vb0 : vb1;
            if (cl < CCH) {
                float4 wA[NU], wB[NU];
#pragma unroll
                for (int d = 0; d < NU; d++) {
                    wA[d] = ws[((cl * NU + d) * 2 + 0) * 16 + uq];
                    wB[d] = ws[((cl * NU + d) * 2 + 1) * 16 + uq];
                }
                float accd[NU];
#pragma unroll
                for (int d = 0; d < NU; d++) accd[d] = 0.0f;
                const int bstag = (cl & 3) * 7;
#pragma unroll 4
                for (int blx = 0; blx < BT; blx++) {
                    const int bl = (blx + bstag) & 63;
                    const float* xp = xs + cl * XSP + bl * IU;
                    float4 x0 = *(const float4*)xp;
                    float4 x1 = *(const float4*)(xp + 4);
                    const float* vp = vb + (size_t)(b0 + bl) * (NU * US) + uq;
#pragma unroll
                    for (int d = 0; d < NU; d++) {
                        float uh = wA[d].x * x0.x + wA[d].y * x0.y + wA[d].z * x0.z + wA[d].w * x0.w
                                 + wB[d].x * x1.x + wB[d].y * x1.y + wB[d].z * x1.z + wB[d].w * x1.w;
                        accd[d] = fmaf(uh, vp[d * US], accd[d]);
                    }
                }
#pragma unroll
                for (int d = 0; d < NU; d++) {
                    float a = accd[d];
                    a += __shfl_xor(a, 1, 64);
                    a += __shfl_xor(a, 2, 64);
                    a += __shfl_xor(a, 4, 64);
                    a += __shfl_xor(a, 8, 64);
                    if (uq == 0)
                        atomicAdd(bij + (size_t)d * IC + c0 + cl, a * (1.0f / (float)B_));
                }
            }
            // __syncthreads drains this block's atomics (vmcnt 0) before the ticket;
            // 4th bt-block of this chunk sees all adds to c0..c0+8 complete.
            __syncthreads();
            if (tid == 0) {
                unsigned old = __hip_atomic_fetch_add(ticket + iter * 128 + ch, 1u,
                                                      __ATOMIC_RELAXED,
                                                      __HIP_MEMORY_SCOPE_AGENT);
                lastflag = (old == 3u);
            }
            __syncthreads();
            if (lastflag && tid < NU) {   // bij for this chunk is final
                float es = 0.0f;
#pragma unroll
                for (int cc = 0; cc < CCH; cc++)
                    es += expf(gld(bij + (size_t)tid * IC + c0 + cc));
                atomicAdd(esum + iter * 16 + tid, es);
            }
        }
        gridbar(bar);   // publishes esum + bij for next iteration's cs prologue
    }
}

extern "C" void kernel_launch(void* const* d_in, const int* in_sizes, int n_in,
                              void* d_out, int out_size, void* d_ws, size_t ws_size,
                              hipStream_t stream) {
    (void)in_sizes; (void)n_in; (void)out_size; (void)ws_size;
    const float* x = (const float*)d_in[0];   // [256, 8, 1152]
    const float* W = (const float*)d_in[1];   // [1, 1152, 10, 16, 8]
    float* out = (float*)d_out;               // [256, 10, 16] fp32

    // workspace: bar(5120 u32) | ticket(256 u32) | esum(32 f) | bij | sp x3 | vb0|vb1
    unsigned* bar = (unsigned*)d_ws;
    unsigned* ticket = bar + 5120;
    float* esum = (float*)(ticket + 256);
    float* bij = esum + 32;
    float* sp  = bij + (size_t)NU * IC;
    float* vb0 = sp + 3 * SPSTRIDE;
    float* vb1 = vb0 + (size_t)B_ * NU * US;

    // zero bar + ticket + esum + bij
    hipMemsetAsync(d_ws, 0, (5120 + 256) * 4 + 32 * 4 + (size_t)NU * IC * 4, stream);
    mega<<<NBLK, 256, 0, stream>>>(x, W, sp, vb0, vb1, bij, esum, ticket, out, bar);
}